// Round 2
// baseline (218.043 us; speedup 1.0000x reference)
//
#include <hip/hip_runtime.h>
#include <hip/hip_bf16.h>

#define N_NODES 50000
#define N_EDGES 800000
#define IN_C 128
#define HC 128
#define HEADS 8
#define NEG_SLOPE 0.2f
#define LN_EPS 1e-5f

#define LDH 136                 // per-wave h-tile row stride (128 + 8 pad)
#define ELL_CAP 64              // slots per node; max degree ~40 (Poisson 16)
#define CNT_STRIDE 16           // 1 counter per 64B line (R1: no effect, kept)
#define GEMM_BLOCKS 782         // ceil(3125 waves / 4)
#define FILL_BLOCKS 391         // 391*256 threads * 8 edges >= 800000

typedef __hip_bfloat16 bf16;
typedef __attribute__((ext_vector_type(8))) short short8;
typedef __attribute__((ext_vector_type(4))) float f32x4;

__device__ __forceinline__ float b2f(bf16 v) { return __bfloat162float(v); }

// float -> bf16 bits, round-to-nearest-even
__device__ __forceinline__ unsigned short f2bf(float f) {
    unsigned u = __float_as_uint(f);
    return (unsigned short)((u + 0x7fffu + ((u >> 16) & 1u)) >> 16);
}
__device__ __forceinline__ float bf2f(unsigned s) {
    return __uint_as_float(s << 16);
}
__device__ __forceinline__ short8 pack8(float4 u, float4 v) {
    short8 r;
    r[0] = (short)f2bf(u.x); r[1] = (short)f2bf(u.y);
    r[2] = (short)f2bf(u.z); r[3] = (short)f2bf(u.w);
    r[4] = (short)f2bf(v.x); r[5] = (short)f2bf(v.y);
    r[6] = (short)f2bf(v.z); r[7] = (short)f2bf(v.w);
    return r;
}

// ---------------------------------------------------------------------------
// prep: W (fp32,[k][n]) -> Wt (bf16,[n][k]) AND zero padded cnt region.
// ---------------------------------------------------------------------------
__global__ __launch_bounds__(256) void prep(
    const float* __restrict__ W, unsigned short* __restrict__ Wt,
    int* __restrict__ cnt)
{
    int id = blockIdx.x * 256 + threadIdx.x;   // 64 blocks * 256 = 16384
    int k = id >> 7, n = id & 127;
    Wt[n * 128 + k] = f2bf(W[id]);
    const int4 z4 = make_int4(0, 0, 0, 0);
    int4* c4 = reinterpret_cast<int4*>(cnt);
    const int total4 = N_NODES * CNT_STRIDE / 4;   // 200000
    for (int j = id; j < total4; j += 64 * 256) c4[j] = z4;
}

// ---------------------------------------------------------------------------
// fill_k (SPLIT from fused for per-phase rocprof attribution):
//   8 consecutive edges/thread -> 8 INDEPENDENT atomic chains in flight.
//   ellp writes via nontemporal store: scattered 4B stores bypass L2 line
//   ownership -> no cross-XCD line ping-pong (suspect for 40MB write ampl).
// ELL entry is 4 B packed {src:16 | ea_bf16:16}.
// ---------------------------------------------------------------------------
__global__ __launch_bounds__(256) void fill_k(
    const int* __restrict__ ei, const float* __restrict__ edge_attr,
    int* __restrict__ cnt, unsigned int* __restrict__ ellp)
{
    const int tid = blockIdx.x * 256 + threadIdx.x;
    const int e0  = tid * 8;
    if (e0 >= N_EDGES) return;
    // 800000 % 8 == 0 and e0 multiple of 8 -> all 8 edges valid
    const int4   sa = *reinterpret_cast<const int4*>(ei + e0);
    const int4   sb = *reinterpret_cast<const int4*>(ei + e0 + 4);
    const int4   da = *reinterpret_cast<const int4*>(ei + N_EDGES + e0);
    const int4   db = *reinterpret_cast<const int4*>(ei + N_EDGES + e0 + 4);
    const float4 aa = *reinterpret_cast<const float4*>(edge_attr + e0);
    const float4 ab = *reinterpret_cast<const float4*>(edge_attr + e0 + 4);

    int p0 = atomicAdd(&cnt[da.x * CNT_STRIDE], 1);
    int p1 = atomicAdd(&cnt[da.y * CNT_STRIDE], 1);
    int p2 = atomicAdd(&cnt[da.z * CNT_STRIDE], 1);
    int p3 = atomicAdd(&cnt[da.w * CNT_STRIDE], 1);
    int p4 = atomicAdd(&cnt[db.x * CNT_STRIDE], 1);
    int p5 = atomicAdd(&cnt[db.y * CNT_STRIDE], 1);
    int p6 = atomicAdd(&cnt[db.z * CNT_STRIDE], 1);
    int p7 = atomicAdd(&cnt[db.w * CNT_STRIDE], 1);

#define PUT(P, D, S, A)                                                    \
    if ((P) < ELL_CAP)                                                     \
        __builtin_nontemporal_store(                                       \
            (((unsigned)(S)) << 16) | (unsigned)f2bf(A),                   \
            &ellp[((D) << 6) + (P)]);
    PUT(p0, da.x, sa.x, aa.x)
    PUT(p1, da.y, sa.y, aa.y)
    PUT(p2, da.z, sa.z, aa.z)
    PUT(p3, da.w, sa.w, aa.w)
    PUT(p4, db.x, sb.x, ab.x)
    PUT(p5, db.y, sb.y, ab.y)
    PUT(p6, db.z, sb.z, ab.z)
    PUT(p7, db.w, sb.w, ab.w)
#undef PUT
}

// ---------------------------------------------------------------------------
// gemm_k (SPLIT from fused): streaming MFMA h = x@W + a_src/a_dst.
// ---------------------------------------------------------------------------
__global__ __launch_bounds__(256) void gemm_k(
    const float* __restrict__ x, const unsigned short* __restrict__ Wt,
    const float* __restrict__ att_src, const float* __restrict__ att_dst,
    unsigned short* __restrict__ h_out,
    float* __restrict__ a_src, float* __restrict__ a_dst)
{
    __shared__ short sH[4][16 * LDH];          // 17408 B
    const int t  = threadIdx.x;
    const int wv = t >> 6;
    const int l  = t & 63;
    const int gw = blockIdx.x * 4 + wv;
    if (gw >= N_NODES / 16) return;            // 3125 active waves, no barriers

    const int n0   = gw * 16;
    const int mrow = l & 15;
    const int quad = l >> 4;

    short8 afrag[4];
    const float* xr = x + (size_t)(n0 + mrow) * IN_C + quad * 8;
#pragma unroll
    for (int ko = 0; ko < 4; ++ko) {
        float4 u = *reinterpret_cast<const float4*>(xr + ko * 32);
        float4 v = *reinterpret_cast<const float4*>(xr + ko * 32 + 4);
        afrag[ko] = pack8(u, v);
    }

    f32x4 acc[8];
#pragma unroll
    for (int nt = 0; nt < 8; ++nt) acc[nt] = (f32x4)0.f;
#pragma unroll
    for (int nt = 0; nt < 8; ++nt) {
        const unsigned short* wr = Wt + (nt * 16 + mrow) * 128 + quad * 8;
#pragma unroll
        for (int ko = 0; ko < 4; ++ko) {
            short8 bfr = *reinterpret_cast<const short8*>(wr + ko * 32);
            acc[nt] = __builtin_amdgcn_mfma_f32_16x16x32_bf16(afrag[ko], bfr, acc[nt], 0, 0, 0);
        }
    }

    // C -> per-wave LDS tile. C/D layout: col = lane&15, row = quad*4 + r.
#pragma unroll
    for (int nt = 0; nt < 8; ++nt)
#pragma unroll
        for (int r = 0; r < 4; ++r)
            sH[wv][(quad * 4 + r) * LDH + nt * 16 + mrow] = (short)f2bf(acc[nt][r]);
    // within-wave LDS write->read: lockstep + compiler lgkmcnt, no barrier

    // h store: 16 rows x 128 cols bf16, 16B per lane per iter
#pragma unroll
    for (int i = 0; i < 4; ++i) {
        int row = i * 4 + (l >> 4);
        int col = (l & 15) * 8;
        short8 hv = *reinterpret_cast<const short8*>(&sH[wv][row * LDH + col]);
        *reinterpret_cast<short8*>(h_out + (size_t)(n0 + row) * HC + col) = hv;
    }

    // a_src/a_dst: 128 (node,head) pairs per wave, 2 per lane
#pragma unroll
    for (int pp = 0; pp < 2; ++pp) {
        int p  = l + pp * 64;
        int m  = p >> 3;
        int hd = p & 7;
        float ssum = 0.f, dsum = 0.f;
#pragma unroll
        for (int c = 0; c < 16; ++c) {
            float hv = bf2f((unsigned short)sH[wv][m * LDH + hd * 16 + c]);
            ssum = fmaf(hv, att_src[hd * 16 + c], ssum);
            dsum = fmaf(hv, att_dst[hd * 16 + c], dsum);
        }
        a_src[(n0 + m) * HEADS + hd] = ssum;
        a_dst[(n0 + m) * HEADS + hd] = dsum;
    }
}

// ---------------------------------------------------------------------------
// gather: single-pass softmax, depth-2 software pipeline — next chunk's ellp
// word AND its a_src are prefetched one iteration ahead, overlapping the
// dependent-load chain (ellp -> a_src) with the current chunk's h-FMA tail.
// ---------------------------------------------------------------------------
__global__ __launch_bounds__(256) void gather_node(
    const int* __restrict__ cnt, const unsigned int* __restrict__ ellp,
    const float* __restrict__ a_src, const float* __restrict__ a_dst,
    const bf16* __restrict__ h,
    const float* __restrict__ x, const float* __restrict__ bvec,
    const float* __restrict__ gamma, const float* __restrict__ beta,
    const float* __restrict__ att_edge, const float* __restrict__ lin_w,
    const float* __restrict__ lin_b,
    float* __restrict__ out)
{
    const int wave = threadIdx.x >> 6;
    const int l    = threadIdx.x & 63;
    const int n    = blockIdx.x * 4 + wave;       // 50000 % 4 == 0
    const int hh   = l >> 3;
    const int jj   = l & 7;

    float ae0 = att_edge[2 * l], ae1 = att_edge[2 * l + 1];
    float p = ae0 * lin_w[2 * l] + ae1 * lin_w[2 * l + 1];
    float q = ae0 * lin_b[2 * l] + ae1 * lin_b[2 * l + 1];
#pragma unroll
    for (int off = 1; off <= 4; off <<= 1) {
        p += __shfl_xor(p, off, 64);
        q += __shfl_xor(q, off, 64);
    }
    const float2 bv = *reinterpret_cast<const float2*>(bvec + 2 * l);
    const float2 gv = *reinterpret_cast<const float2*>(gamma + 2 * l);
    const float2 be = *reinterpret_cast<const float2*>(beta + 2 * l);

    const float ad  = a_dst[n * HEADS + hh];
    const int   beg = n << 6;
    const int   cn  = min(cnt[n * CNT_STRIDE], ELL_CAP);
    const int   full = cn & ~7;

    float zp = 0.f, acc0 = 0.f, acc1 = 0.f;
    const __hip_bfloat162* h2 = reinterpret_cast<const __hip_bfloat162*>(h);

    if (full > 0) {
        // pipeline prologue: chunk 0's ell word + its a_src
        unsigned ce_c = ellp[beg + jj];
        float    as_c = a_src[(ce_c >> 16) * HEADS + hh];

        for (int bs = 0; bs < full; bs += 8) {
            const unsigned ce = ce_c;
            const float    as = as_c;
            // prefetch next chunk (ellp padded by 256B -> unconditional OK)
            ce_c = ellp[beg + bs + 8 + jj];

            const int   sl = ce >> 16;
            const float ea = bf2f(ce & 0xffffu);
            float lg = as + ad + ea * p + q;
            lg = lg > 0.f ? lg : NEG_SLOPE * lg;
            const float ev = __expf(lg);
            zp += ev;
            const int pk = (sl << 16) | (int)f2bf(ev);   // {src:16 | ev_bf16:16}

            as_c = a_src[(ce_c >> 16) * HEADS + hh];     // next chunk's a_src

            // broadcast lane (l&56)|j within each 8-lane head group
#define GSTEP(OFF)                                                        \
            {                                                             \
                int pj = __builtin_amdgcn_ds_swizzle(pk, OFF);            \
                int sj = ((unsigned)pj) >> 16;                            \
                float evj = bf2f((unsigned)pj & 0xffffu);                 \
                __hip_bfloat162 hv = h2[(size_t)sj * 64 + l];             \
                acc0 += evj * b2f(hv.x);                                  \
                acc1 += evj * b2f(hv.y);                                  \
            }
            GSTEP(24)  GSTEP(56)  GSTEP(88)  GSTEP(120)
            GSTEP(152) GSTEP(184) GSTEP(216) GSTEP(248)
#undef GSTEP
        }
    }

    const int rem = cn - full;
    if (rem > 0) {
        int sl = 0; float ev = 0.f;
        if (jj < rem) {
            unsigned ce = ellp[beg + full + jj];
            sl = ce >> 16;
            float ea = bf2f(ce & 0xffffu);
            float lg = a_src[sl * HEADS + hh] + ad + ea * p + q;
            lg = lg > 0.f ? lg : NEG_SLOPE * lg;
            ev = __expf(lg);
        }
        zp += ev;
        const int gbase = l & 56;
        for (int j = 0; j < rem; ++j) {
            float evj = __shfl(ev, gbase | j, 64);
            int   sj  = __shfl(sl, gbase | j, 64);
            __hip_bfloat162 hv = h2[(size_t)sj * 64 + l];
            acc0 += evj * b2f(hv.x);
            acc1 += evj * b2f(hv.y);
        }
    }

    // z: reduce per-lane partials across the 8 lanes of this head group
    float z = zp;
    z += __shfl_xor(z, 1, 64);
    z += __shfl_xor(z, 2, 64);
    z += __shfl_xor(z, 4, 64);
    const float rz = 1.f / (z + 1e-16f);
    acc0 *= rz;
    acc1 *= rz;

    const size_t idx = (size_t)n * HC + 2 * l;
    const float2 xv = *reinterpret_cast<const float2*>(x + idx);
    float v0 = acc0 + xv.x + bv.x;
    float v1 = acc1 + xv.y + bv.y;
    float s1 = v0 + v1, s2 = v0 * v0 + v1 * v1;
#pragma unroll
    for (int off = 32; off >= 1; off >>= 1) {
        s1 += __shfl_xor(s1, off, 64);
        s2 += __shfl_xor(s2, off, 64);
    }
    const float mean = s1 * (1.f / HC);
    const float var  = s2 * (1.f / HC) - mean * mean;
    const float inv  = rsqrtf(var + LN_EPS);
    float y0 = (v0 - mean) * inv * gv.x + be.x;
    float y1 = (v1 - mean) * inv * gv.y + be.y;
    y0 = y0 > 0.f ? y0 : expm1f(y0);
    y1 = y1 > 0.f ? y1 : expm1f(y1);
    *reinterpret_cast<float2*>(out + idx) = make_float2(y0, y1);
}

// ---------------------------------------------------------------------------
extern "C" void kernel_launch(void* const* d_in, const int* in_sizes, int n_in,
                              void* d_out, int out_size, void* d_ws, size_t ws_size,
                              hipStream_t stream)
{
    const float* x         = (const float*)d_in[0];
    const int*   ei        = (const int*)d_in[1];
    const float* edge_attr = (const float*)d_in[2];
    const float* W         = (const float*)d_in[3];
    const float* b         = (const float*)d_in[4];
    const float* att_src   = (const float*)d_in[5];
    const float* att_dst   = (const float*)d_in[6];
    const float* att_edge  = (const float*)d_in[7];
    const float* lin_w     = (const float*)d_in[8];
    const float* lin_b     = (const float*)d_in[9];
    const float* gamma     = (const float*)d_in[10];
    const float* beta      = (const float*)d_in[11];

    char* ws = (char*)d_ws;
    bf16*  h     = (bf16*)ws;  ws += (size_t)N_NODES * HC * sizeof(bf16);      // 12.8 MB
    float* a_src = (float*)ws; ws += (size_t)N_NODES * HEADS * sizeof(float);  //  1.6 MB
    float* a_dst = (float*)ws; ws += (size_t)N_NODES * HEADS * sizeof(float);  //  1.6 MB
    int*   cnt   = (int*)ws;   ws += (size_t)N_NODES * CNT_STRIDE * sizeof(int); // 3.2 MB
    unsigned short* Wt = (unsigned short*)ws;
    ws += (size_t)128 * 128 * sizeof(unsigned short);                          //  32 KB
    unsigned int* ellp = (unsigned int*)ws;
    ws += (size_t)(N_NODES * ELL_CAP + 64) * sizeof(unsigned int);             // 12.8 MB + pad

    prep<<<64, 256, 0, stream>>>(W, Wt, cnt);

    fill_k<<<FILL_BLOCKS, 256, 0, stream>>>(ei, edge_attr, cnt, ellp);

    gemm_k<<<GEMM_BLOCKS, 256, 0, stream>>>(
        x, Wt, att_src, att_dst, (unsigned short*)h, a_src, a_dst);

    gather_node<<<N_NODES / 4, 256, 0, stream>>>(
        cnt, ellp, a_src, a_dst, h, x, b, gamma, beta,
        att_edge, lin_w, lin_b, (float*)d_out);
}

// Round 3
// 188.086 us; speedup vs baseline: 1.1593x; 1.1593x over previous
//
#include <hip/hip_runtime.h>
#include <hip/hip_bf16.h>

#define N_NODES 50000
#define N_EDGES 800000
#define IN_C 128
#define HC 128
#define HEADS 8
#define NEG_SLOPE 0.2f
#define LN_EPS 1e-5f

#define LDH 136                 // per-wave h-tile row stride (128 + 8 pad)
#define ELL_CAP 64              // slots per node; max degree ~40 (Poisson 16)
#define GEMM_BLOCKS 782         // ceil(3125 waves / 4)
#define FILL_BLOCKS 782         // 782*256 threads * 4 edges >= 800000
#define FUSED_BLOCKS (GEMM_BLOCKS + FILL_BLOCKS)   // 1564: all co-resident

typedef __hip_bfloat16 bf16;
typedef __attribute__((ext_vector_type(8))) short short8;
typedef __attribute__((ext_vector_type(4))) float f32x4;

__device__ __forceinline__ float b2f(bf16 v) { return __bfloat162float(v); }

// float -> bf16 bits, round-to-nearest-even
__device__ __forceinline__ unsigned short f2bf(float f) {
    unsigned u = __float_as_uint(f);
    return (unsigned short)((u + 0x7fffu + ((u >> 16) & 1u)) >> 16);
}
__device__ __forceinline__ float bf2f(unsigned s) {
    return __uint_as_float(s << 16);
}
__device__ __forceinline__ short8 pack8(float4 u, float4 v) {
    short8 r;
    r[0] = (short)f2bf(u.x); r[1] = (short)f2bf(u.y);
    r[2] = (short)f2bf(u.z); r[3] = (short)f2bf(u.w);
    r[4] = (short)f2bf(v.x); r[5] = (short)f2bf(v.y);
    r[6] = (short)f2bf(v.z); r[7] = (short)f2bf(v.w);
    return r;
}

// ---------------------------------------------------------------------------
// prep: W (fp32,[k][n]) -> Wt (bf16,[n][k]) AND zero cnt (replaces memset).
// ---------------------------------------------------------------------------
__global__ __launch_bounds__(256) void prep(
    const float* __restrict__ W, unsigned short* __restrict__ Wt,
    int* __restrict__ cnt)
{
    int id = blockIdx.x * 256 + threadIdx.x;   // 64 blocks * 256 = 16384
    int k = id >> 7, n = id & 127;
    Wt[n * 128 + k] = f2bf(W[id]);
#pragma unroll
    for (int i = 0; i < 4; ++i) {
        int j = id + i * 16384;
        if (j < N_NODES) cnt[j] = 0;
    }
}

// ---------------------------------------------------------------------------
// fused: heterogeneous blocks (interleaved even/odd for even CU spread).
//   bid even -> GEMM block (782): streaming MFMA h = x@W + a_src/a_dst.
//   bid odd  -> ELL-fill block (782): 4 consecutive edges/thread ->
//               int4/float4 loads + 4 INDEPENDENT atomic chains in flight.
//               ellp writes nontemporal: scattered 4B stores skip L2 line
//               ownership -> less cross-XCD write ping-pong.
// ELL entry is 4 B packed {src:16 | ea_bf16:16}.
// ---------------------------------------------------------------------------
__global__ __launch_bounds__(256) void fused(
    const float* __restrict__ x, const unsigned short* __restrict__ Wt,
    const float* __restrict__ att_src, const float* __restrict__ att_dst,
    const int* __restrict__ ei, const float* __restrict__ edge_attr,
    int* __restrict__ cnt, unsigned int* __restrict__ ellp,
    unsigned short* __restrict__ h_out,
    float* __restrict__ a_src, float* __restrict__ a_dst)
{
    __shared__ short sH[4][16 * LDH];          // 17408 B (gemm blocks only)
    const int bid = blockIdx.x;
    const int t   = threadIdx.x;

    if (bid & 1) {
        // ---------------- ELL fill: 4 edges per thread ----------------
        const int fid = bid >> 1;              // 0..781
        const int e0  = (fid * 256 + t) * 4;
        if (e0 >= N_EDGES) return;
        // 800000 % 4 == 0 and e0 multiple of 4 -> all 4 edges valid
        const int4   s4 = *reinterpret_cast<const int4*>(ei + e0);
        const int4   d4 = *reinterpret_cast<const int4*>(ei + N_EDGES + e0);
        const float4 a4 = *reinterpret_cast<const float4*>(edge_attr + e0);

        int p0 = atomicAdd(&cnt[d4.x], 1);
        int p1 = atomicAdd(&cnt[d4.y], 1);
        int p2 = atomicAdd(&cnt[d4.z], 1);
        int p3 = atomicAdd(&cnt[d4.w], 1);
#define PUT(P, D, S, A)                                                    \
        if ((P) < ELL_CAP)                                                 \
            __builtin_nontemporal_store(                                   \
                (((unsigned)(S)) << 16) | (unsigned)f2bf(A),               \
                &ellp[((D) << 6) + (P)]);
        PUT(p0, d4.x, s4.x, a4.x)
        PUT(p1, d4.y, s4.y, a4.y)
        PUT(p2, d4.z, s4.z, a4.z)
        PUT(p3, d4.w, s4.w, a4.w)
#undef PUT
        return;
    }

    // ---------------- GEMM ----------------
    const int gid = bid >> 1;                  // 0..781
    const int wv  = t >> 6;
    const int l   = t & 63;
    const int gw  = gid * 4 + wv;
    if (gw >= N_NODES / 16) return;            // 3125 active waves, no barriers

    const int n0   = gw * 16;
    const int mrow = l & 15;
    const int quad = l >> 4;

    short8 afrag[4];
    const float* xr = x + (size_t)(n0 + mrow) * IN_C + quad * 8;
#pragma unroll
    for (int ko = 0; ko < 4; ++ko) {
        float4 u = *reinterpret_cast<const float4*>(xr + ko * 32);
        float4 v = *reinterpret_cast<const float4*>(xr + ko * 32 + 4);
        afrag[ko] = pack8(u, v);
    }

    f32x4 acc[8];
#pragma unroll
    for (int nt = 0; nt < 8; ++nt) acc[nt] = (f32x4)0.f;
#pragma unroll
    for (int nt = 0; nt < 8; ++nt) {
        const unsigned short* wr = Wt + (nt * 16 + mrow) * 128 + quad * 8;
#pragma unroll
        for (int ko = 0; ko < 4; ++ko) {
            short8 bfr = *reinterpret_cast<const short8*>(wr + ko * 32);
            acc[nt] = __builtin_amdgcn_mfma_f32_16x16x32_bf16(afrag[ko], bfr, acc[nt], 0, 0, 0);
        }
    }

    // C -> per-wave LDS tile. C/D layout: col = lane&15, row = quad*4 + r.
#pragma unroll
    for (int nt = 0; nt < 8; ++nt)
#pragma unroll
        for (int r = 0; r < 4; ++r)
            sH[wv][(quad * 4 + r) * LDH + nt * 16 + mrow] = (short)f2bf(acc[nt][r]);
    // within-wave LDS write->read: lockstep + compiler lgkmcnt, no barrier

    // h store: 16 rows x 128 cols bf16, 16B per lane per iter
#pragma unroll
    for (int i = 0; i < 4; ++i) {
        int row = i * 4 + (l >> 4);
        int col = (l & 15) * 8;
        short8 hv = *reinterpret_cast<const short8*>(&sH[wv][row * LDH + col]);
        *reinterpret_cast<short8*>(h_out + (size_t)(n0 + row) * HC + col) = hv;
    }

    // a_src/a_dst: 128 (node,head) pairs per wave, 2 per lane
#pragma unroll
    for (int pp = 0; pp < 2; ++pp) {
        int p  = l + pp * 64;
        int m  = p >> 3;
        int hd = p & 7;
        float ssum = 0.f, dsum = 0.f;
#pragma unroll
        for (int c = 0; c < 16; ++c) {
            float hv = bf2f((unsigned short)sH[wv][m * LDH + hd * 16 + c]);
            ssum = fmaf(hv, att_src[hd * 16 + c], ssum);
            dsum = fmaf(hv, att_dst[hd * 16 + c], dsum);
        }
        a_src[(n0 + m) * HEADS + hd] = ssum;
        a_dst[(n0 + m) * HEADS + hd] = dsum;
    }
}

// ---------------------------------------------------------------------------
// gather: single-pass softmax, depth-2 pipeline on EVERYTHING including the
// h rows: next chunk's ellp word, a_src, AND its 8 h-rows are issued before
// the current chunk's softmax+FMA block (h address depends only on the ellp
// word, not on ev). Tail is folded into the uniform 8-wide chunk machinery
// with per-lane ev=0 masking; invalid slots clamp to h row 0 (L2-hot dummy)
// so no garbage fetch. No serial remainder loop.
// ---------------------------------------------------------------------------

// swizzle offset (j<<5)|24: lane' = (lane & 56) | j  (broadcast within the
// 8-lane head group; bit 5 preserved by per-32-lane ds_swizzle semantics)
#define LROW(CE, HV, J, OFF, B0)                                           \
    { int cj_ = __builtin_amdgcn_ds_swizzle((int)(CE), OFF);               \
      size_t r_ = ((B0) + (J) < cn) ? (size_t)(((unsigned)cj_) >> 16) : 0; \
      (HV)[J] = h2[r_ * 64 + l]; }
#define LOADROWS(CE, HV, B0)                                               \
    LROW(CE, HV, 0,  24, B0) LROW(CE, HV, 1,  56, B0)                      \
    LROW(CE, HV, 2,  88, B0) LROW(CE, HV, 3, 120, B0)                      \
    LROW(CE, HV, 4, 152, B0) LROW(CE, HV, 5, 184, B0)                      \
    LROW(CE, HV, 6, 216, B0) LROW(CE, HV, 7, 248, B0)

#define FROW(EV, HV, J, OFF)                                               \
    { float evj_ = __uint_as_float((unsigned)__builtin_amdgcn_ds_swizzle(  \
          __float_as_int(EV), OFF));                                       \
      acc0 = fmaf(evj_, b2f((HV)[J].x), acc0);                             \
      acc1 = fmaf(evj_, b2f((HV)[J].y), acc1); }
#define FMAROWS(EV, HV)                                                    \
    FROW(EV, HV, 0,  24) FROW(EV, HV, 1,  56) FROW(EV, HV, 2,  88)        \
    FROW(EV, HV, 3, 120) FROW(EV, HV, 4, 152) FROW(EV, HV, 5, 184)        \
    FROW(EV, HV, 6, 216) FROW(EV, HV, 7, 248)

__global__ __launch_bounds__(256) void gather_node(
    const int* __restrict__ cnt, const unsigned int* __restrict__ ellp,
    const float* __restrict__ a_src, const float* __restrict__ a_dst,
    const bf16* __restrict__ h,
    const float* __restrict__ x, const float* __restrict__ bvec,
    const float* __restrict__ gamma, const float* __restrict__ beta,
    const float* __restrict__ att_edge, const float* __restrict__ lin_w,
    const float* __restrict__ lin_b,
    float* __restrict__ out)
{
    const int wave = threadIdx.x >> 6;
    const int l    = threadIdx.x & 63;
    const int n    = blockIdx.x * 4 + wave;       // 50000 % 4 == 0
    const int hh   = l >> 3;
    const int jj   = l & 7;

    float ae0 = att_edge[2 * l], ae1 = att_edge[2 * l + 1];
    float p = ae0 * lin_w[2 * l] + ae1 * lin_w[2 * l + 1];
    float q = ae0 * lin_b[2 * l] + ae1 * lin_b[2 * l + 1];
#pragma unroll
    for (int off = 1; off <= 4; off <<= 1) {
        p += __shfl_xor(p, off, 64);
        q += __shfl_xor(q, off, 64);
    }
    const float2 bv = *reinterpret_cast<const float2*>(bvec + 2 * l);
    const float2 gv = *reinterpret_cast<const float2*>(gamma + 2 * l);
    const float2 be = *reinterpret_cast<const float2*>(beta + 2 * l);

    const float adq = a_dst[n * HEADS + hh] + q;
    const int   beg = n << 6;
    const int   cn  = min(cnt[n], ELL_CAP);

    float zp = 0.f, acc0 = 0.f, acc1 = 0.f;
    const __hip_bfloat162* h2 = reinterpret_cast<const __hip_bfloat162*>(h);

    if (cn > 0) {
        // pipeline prologue: chunk 0's ell word, a_src, and 8 h rows
        unsigned ce_c = ellp[beg + jj];
        float    as_c = a_src[(ce_c >> 16) * HEADS + hh];
        __hip_bfloat162 hv_c[8], hv_n[8];
        LOADROWS(ce_c, hv_c, 0)

        for (int bs = 0; ; bs += 8) {
            const unsigned ce   = ce_c;
            const float    as   = as_c;
            const bool     last = (bs + 8 >= cn);   // wave-uniform
            if (!last) {
                // issue next chunk's loads BEFORE this chunk's compute:
                // 8 h-rows + a_src stay in flight across the FMA block
                ce_c = ellp[beg + bs + 8 + jj];
                LOADROWS(ce_c, hv_n, bs + 8)
                as_c = a_src[(ce_c >> 16) * HEADS + hh];
            }
            const float ea = bf2f(ce & 0xffffu);
            float lg = fmaf(ea, p, as + adq);
            lg = fmaxf(lg, NEG_SLOPE * lg);         // leaky_relu, branchless
            const float ev = (bs + jj < cn) ? __expf(lg) : 0.f;
            zp += ev;
            FMAROWS(ev, hv_c)
            if (last) break;
#pragma unroll
            for (int j = 0; j < 8; ++j) hv_c[j] = hv_n[j];
        }
    }

    // z: reduce per-lane partials across the 8 lanes of this head group
    float z = zp;
    z += __shfl_xor(z, 1, 64);
    z += __shfl_xor(z, 2, 64);
    z += __shfl_xor(z, 4, 64);
    const float rz = 1.f / (z + 1e-16f);
    acc0 *= rz;
    acc1 *= rz;

    const size_t idx = (size_t)n * HC + 2 * l;
    const float2 xv = *reinterpret_cast<const float2*>(x + idx);
    float v0 = acc0 + xv.x + bv.x;
    float v1 = acc1 + xv.y + bv.y;
    float s1 = v0 + v1, s2 = v0 * v0 + v1 * v1;
#pragma unroll
    for (int off = 32; off >= 1; off >>= 1) {
        s1 += __shfl_xor(s1, off, 64);
        s2 += __shfl_xor(s2, off, 64);
    }
    const float mean = s1 * (1.f / HC);
    const float var  = s2 * (1.f / HC) - mean * mean;
    const float inv  = rsqrtf(var + LN_EPS);
    float y0 = (v0 - mean) * inv * gv.x + be.x;
    float y1 = (v1 - mean) * inv * gv.y + be.y;
    y0 = y0 > 0.f ? y0 : expm1f(y0);
    y1 = y1 > 0.f ? y1 : expm1f(y1);
    *reinterpret_cast<float2*>(out + idx) = make_float2(y0, y1);
}

// ---------------------------------------------------------------------------
extern "C" void kernel_launch(void* const* d_in, const int* in_sizes, int n_in,
                              void* d_out, int out_size, void* d_ws, size_t ws_size,
                              hipStream_t stream)
{
    const float* x         = (const float*)d_in[0];
    const int*   ei        = (const int*)d_in[1];
    const float* edge_attr = (const float*)d_in[2];
    const float* W         = (const float*)d_in[3];
    const float* b         = (const float*)d_in[4];
    const float* att_src   = (const float*)d_in[5];
    const float* att_dst   = (const float*)d_in[6];
    const float* att_edge  = (const float*)d_in[7];
    const float* lin_w     = (const float*)d_in[8];
    const float* lin_b     = (const float*)d_in[9];
    const float* gamma     = (const float*)d_in[10];
    const float* beta      = (const float*)d_in[11];

    char* ws = (char*)d_ws;
    bf16*  h     = (bf16*)ws;  ws += (size_t)N_NODES * HC * sizeof(bf16);      // 12.8 MB
    float* a_src = (float*)ws; ws += (size_t)N_NODES * HEADS * sizeof(float);  //  1.6 MB
    float* a_dst = (float*)ws; ws += (size_t)N_NODES * HEADS * sizeof(float);  //  1.6 MB
    int*   cnt   = (int*)ws;   ws += (size_t)N_NODES * sizeof(int);            //  0.2 MB
    unsigned short* Wt = (unsigned short*)ws;
    ws += (size_t)128 * 128 * sizeof(unsigned short);                          //  32 KB
    unsigned int* ellp = (unsigned int*)ws;
    ws += (size_t)(N_NODES * ELL_CAP + 64) * sizeof(unsigned int);             // 12.8 MB + pad

    prep<<<64, 256, 0, stream>>>(W, Wt, cnt);

    fused<<<FUSED_BLOCKS, 256, 0, stream>>>(
        x, Wt, att_src, att_dst, ei, edge_attr, cnt, ellp,
        (unsigned short*)h, a_src, a_dst);

    gather_node<<<N_NODES / 4, 256, 0, stream>>>(
        cnt, ellp, a_src, a_dst, h, x, b, gamma, beta,
        att_edge, lin_w, lin_b, (float*)d_out);
}

// Round 7
// 187.684 us; speedup vs baseline: 1.1618x; 1.0021x over previous
//
#include <hip/hip_runtime.h>
#include <hip/hip_bf16.h>

#define N_NODES 50000
#define N_EDGES 800000
#define IN_C 128
#define HC 128
#define HEADS 8
#define NEG_SLOPE 0.2f
#define LN_EPS 1e-5f

#define LDH 136                 // per-wave h-tile row stride (128 + 8 pad)
#define ELL_CAP 64              // slots per node; max degree ~40 (Poisson 16)
#define CHUNK_E 8192            // edges per fill chunk (98 chunks)
#define N_CHUNKS 98             // 98*8192 = 802816 >= 800000
#define FUSED_BLOCKS 1568       // 196 groups of 8; even groups GEMM (784),
                                // odd groups fill (784, 8 classes x 98 chunks)
// cnt is class-contiguous so one 64B line never mixes XCD classes:
// cperm(n) = (n&7)*6256 + (n>>3); 8*6256 = 50048 ints, class base 64B-aligned
#define CNT_SIZE 50048

typedef __hip_bfloat16 bf16;
typedef __attribute__((ext_vector_type(8))) short short8;
typedef __attribute__((ext_vector_type(4))) float f32x4;

__device__ __forceinline__ float b2f(bf16 v) { return __bfloat162float(v); }
__device__ __forceinline__ int cperm(int n) { return (n & 7) * 6256 + (n >> 3); }

// float -> bf16 bits, round-to-nearest-even
__device__ __forceinline__ unsigned short f2bf(float f) {
    unsigned u = __float_as_uint(f);
    return (unsigned short)((u + 0x7fffu + ((u >> 16) & 1u)) >> 16);
}
__device__ __forceinline__ float bf2f(unsigned s) {
    return __uint_as_float(s << 16);
}
__device__ __forceinline__ short8 pack8(float4 u, float4 v) {
    short8 r;
    r[0] = (short)f2bf(u.x); r[1] = (short)f2bf(u.y);
    r[2] = (short)f2bf(u.z); r[3] = (short)f2bf(u.w);
    r[4] = (short)f2bf(v.x); r[5] = (short)f2bf(v.y);
    r[6] = (short)f2bf(v.z); r[7] = (short)f2bf(v.w);
    return r;
}

// ---------------------------------------------------------------------------
// prep: W (fp32,[k][n]) -> Wt (bf16,[n][k]) AND zero cnt (class-permuted).
// ---------------------------------------------------------------------------
__global__ __launch_bounds__(256) void prep(
    const float* __restrict__ W, unsigned short* __restrict__ Wt,
    int* __restrict__ cnt)
{
    int id = blockIdx.x * 256 + threadIdx.x;   // 64 blocks * 256 = 16384
    int k = id >> 7, n = id & 127;
    Wt[n * 128 + k] = f2bf(W[id]);
#pragma unroll
    for (int i = 0; i < 4; ++i) {
        int j = id + i * 16384;
        if (j < CNT_SIZE) cnt[j] = 0;
    }
}

// ---------------------------------------------------------------------------
// fused: heterogeneous groups-of-8 blocks (all 8 XCDs get both roles).
//   grp = bid>>3 even -> GEMM block: streaming MFMA h = x@W + a_src/a_dst.
//   grp odd -> XCD-LOCAL ELL fill: the 8 blocks of a group (one per XCD,
//     class = bid&7 = dst&7 it owns) all scan the SAME 8192-edge chunk and
//     keep only their class's edges. Every cnt/ellp line is then touched by
//     exactly ONE XCD -> L2 line ownership acquired once, atomics are local
//     L2 hits, no per-atomic cross-XCD line migration (R3: migrations were
//     ~45MB of write-back = the fill bottleneck). Cost: 8x edge reads (L3).
// ELL entry is 4 B packed {src:16 | ea_bf16:16}.
// ---------------------------------------------------------------------------
__global__ __launch_bounds__(256) void fused(
    const float* __restrict__ x, const unsigned short* __restrict__ Wt,
    const float* __restrict__ att_src, const float* __restrict__ att_dst,
    const int* __restrict__ ei, const float* __restrict__ edge_attr,
    int* __restrict__ cnt, unsigned int* __restrict__ ellp,
    unsigned short* __restrict__ h_out,
    float* __restrict__ a_src, float* __restrict__ a_dst)
{
    __shared__ short sH[4][16 * LDH];          // 17408 B (gemm blocks only)
    const int bid = blockIdx.x;
    const int t   = threadIdx.x;
    const int grp = bid >> 3;                  // 0..195
    const int sub = bid & 7;                   // XCD residue / class

    if (grp & 1) {
        // ---------- XCD-local ELL fill: scan chunk, keep class==sub -------
        const int chunk = grp >> 1;            // 0..97
        const int base  = chunk * CHUNK_E;
#define PROC(D, S, A)                                                      \
        if ((((D) & 7) == sub)) {                                          \
            int p_ = atomicAdd(&cnt[cperm(D)], 1);                         \
            if (p_ < ELL_CAP)                                              \
                ellp[((D) << 6) + p_] =                                    \
                    (((unsigned)(S)) << 16) | (unsigned)f2bf(A);           \
        }
#pragma unroll
        for (int i = 0; i < 8; ++i) {
            const int e = base + i * 1024 + t * 4;
            if (e < N_EDGES) {                 // N_EDGES%4==0 -> int4 safe
                const int4   s4 = *reinterpret_cast<const int4*>(ei + e);
                const int4   d4 = *reinterpret_cast<const int4*>(ei + N_EDGES + e);
                const float4 a4 = *reinterpret_cast<const float4*>(edge_attr + e);
                PROC(d4.x, s4.x, a4.x)
                PROC(d4.y, s4.y, a4.y)
                PROC(d4.z, s4.z, a4.z)
                PROC(d4.w, s4.w, a4.w)
            }
        }
#undef PROC
        return;
    }

    // ---------------- GEMM ----------------
    const int gid = (grp >> 1) * 8 + sub;      // 0..783
    const int wv  = t >> 6;
    const int l   = t & 63;
    const int gw  = gid * 4 + wv;
    if (gw >= N_NODES / 16) return;            // 3125 active waves, no barriers

    const int n0   = gw * 16;
    const int mrow = l & 15;
    const int quad = l >> 4;

    short8 afrag[4];
    const float* xr = x + (size_t)(n0 + mrow) * IN_C + quad * 8;
#pragma unroll
    for (int ko = 0; ko < 4; ++ko) {
        float4 u = *reinterpret_cast<const float4*>(xr + ko * 32);
        float4 v = *reinterpret_cast<const float4*>(xr + ko * 32 + 4);
        afrag[ko] = pack8(u, v);
    }

    f32x4 acc[8];
#pragma unroll
    for (int nt = 0; nt < 8; ++nt) acc[nt] = (f32x4)0.f;
#pragma unroll
    for (int nt = 0; nt < 8; ++nt) {
        const unsigned short* wr = Wt + (nt * 16 + mrow) * 128 + quad * 8;
#pragma unroll
        for (int ko = 0; ko < 4; ++ko) {
            short8 bfr = *reinterpret_cast<const short8*>(wr + ko * 32);
            acc[nt] = __builtin_amdgcn_mfma_f32_16x16x32_bf16(afrag[ko], bfr, acc[nt], 0, 0, 0);
        }
    }

    // C -> per-wave LDS tile. C/D layout: col = lane&15, row = quad*4 + r.
#pragma unroll
    for (int nt = 0; nt < 8; ++nt)
#pragma unroll
        for (int r = 0; r < 4; ++r)
            sH[wv][(quad * 4 + r) * LDH + nt * 16 + mrow] = (short)f2bf(acc[nt][r]);
    // within-wave LDS write->read: lockstep + compiler lgkmcnt, no barrier

    // h store: 16 rows x 128 cols bf16, 16B per lane per iter
#pragma unroll
    for (int i = 0; i < 4; ++i) {
        int row = i * 4 + (l >> 4);
        int col = (l & 15) * 8;
        short8 hv = *reinterpret_cast<const short8*>(&sH[wv][row * LDH + col]);
        *reinterpret_cast<short8*>(h_out + (size_t)(n0 + row) * HC + col) = hv;
    }

    // a_src/a_dst: 128 (node,head) pairs per wave, 2 per lane
#pragma unroll
    for (int pp = 0; pp < 2; ++pp) {
        int p  = l + pp * 64;
        int m  = p >> 3;
        int hd = p & 7;
        float ssum = 0.f, dsum = 0.f;
#pragma unroll
        for (int c = 0; c < 16; ++c) {
            float hv = bf2f((unsigned short)sH[wv][m * LDH + hd * 16 + c]);
            ssum = fmaf(hv, att_src[hd * 16 + c], ssum);
            dsum = fmaf(hv, att_dst[hd * 16 + c], dsum);
        }
        a_src[(n0 + m) * HEADS + hd] = ssum;
        a_dst[(n0 + m) * HEADS + hd] = dsum;
    }
}

// ---------------------------------------------------------------------------
// gather: single-pass softmax, depth-2 pipeline on EVERYTHING including the
// h rows: next chunk's ellp word, a_src, AND its 8 h-rows are issued before
// the current chunk's softmax+FMA block. Tail folded into the uniform 8-wide
// chunk machinery with ev=0 masking; invalid slots clamp to h row 0.
// ---------------------------------------------------------------------------

// swizzle offset (j<<5)|24: lane' = (lane & 56) | j  (broadcast within the
// 8-lane head group; bit 5 preserved by per-32-lane ds_swizzle semantics)
#define LROW(CE, HV, J, OFF, B0)                                           \
    { int cj_ = __builtin_amdgcn_ds_swizzle((int)(CE), OFF);               \
      size_t r_ = ((B0) + (J) < cn) ? (size_t)(((unsigned)cj_) >> 16) : 0; \
      (HV)[J] = h2[r_ * 64 + l]; }
#define LOADROWS(CE, HV, B0)                                               \
    LROW(CE, HV, 0,  24, B0) LROW(CE, HV, 1,  56, B0)                      \
    LROW(CE, HV, 2,  88, B0) LROW(CE, HV, 3, 120, B0)                      \
    LROW(CE, HV, 4, 152, B0) LROW(CE, HV, 5, 184, B0)                      \
    LROW(CE, HV, 6, 216, B0) LROW(CE, HV, 7, 248, B0)

#define FROW(EV, HV, J, OFF)                                               \
    { float evj_ = __uint_as_float((unsigned)__builtin_amdgcn_ds_swizzle(  \
          __float_as_int(EV), OFF));                                       \
      acc0 = fmaf(evj_, b2f((HV)[J].x), acc0);                             \
      acc1 = fmaf(evj_, b2f((HV)[J].y), acc1); }
#define FMAROWS(EV, HV)                                                    \
    FROW(EV, HV, 0,  24) FROW(EV, HV, 1,  56) FROW(EV, HV, 2,  88)        \
    FROW(EV, HV, 3, 120) FROW(EV, HV, 4, 152) FROW(EV, HV, 5, 184)        \
    FROW(EV, HV, 6, 216) FROW(EV, HV, 7, 248)

__global__ __launch_bounds__(256) void gather_node(
    const int* __restrict__ cnt, const unsigned int* __restrict__ ellp,
    const float* __restrict__ a_src, const float* __restrict__ a_dst,
    const bf16* __restrict__ h,
    const float* __restrict__ x, const float* __restrict__ bvec,
    const float* __restrict__ gamma, const float* __restrict__ beta,
    const float* __restrict__ att_edge, const float* __restrict__ lin_w,
    const float* __restrict__ lin_b,
    float* __restrict__ out)
{
    const int wave = threadIdx.x >> 6;
    const int l    = threadIdx.x & 63;
    const int n    = blockIdx.x * 4 + wave;       // 50000 % 4 == 0
    const int hh   = l >> 3;
    const int jj   = l & 7;

    float ae0 = att_edge[2 * l], ae1 = att_edge[2 * l + 1];
    float p = ae0 * lin_w[2 * l] + ae1 * lin_w[2 * l + 1];
    float q = ae0 * lin_b[2 * l] + ae1 * lin_b[2 * l + 1];
#pragma unroll
    for (int off = 1; off <= 4; off <<= 1) {
        p += __shfl_xor(p, off, 64);
        q += __shfl_xor(q, off, 64);
    }
    const float2 bv = *reinterpret_cast<const float2*>(bvec + 2 * l);
    const float2 gv = *reinterpret_cast<const float2*>(gamma + 2 * l);
    const float2 be = *reinterpret_cast<const float2*>(beta + 2 * l);

    const float adq = a_dst[n * HEADS + hh] + q;
    const int   beg = n << 6;
    const int   cn  = min(cnt[cperm(n)], ELL_CAP);

    float zp = 0.f, acc0 = 0.f, acc1 = 0.f;
    const __hip_bfloat162* h2 = reinterpret_cast<const __hip_bfloat162*>(h);

    if (cn > 0) {
        // pipeline prologue: chunk 0's ell word, a_src, and 8 h rows
        unsigned ce_c = ellp[beg + jj];
        float    as_c = a_src[(ce_c >> 16) * HEADS + hh];
        __hip_bfloat162 hv_c[8], hv_n[8];
        LOADROWS(ce_c, hv_c, 0)

        for (int bs = 0; ; bs += 8) {
            const unsigned ce   = ce_c;
            const float    as   = as_c;
            const bool     last = (bs + 8 >= cn);   // wave-uniform
            if (!last) {
                // issue next chunk's loads BEFORE this chunk's compute:
                // 8 h-rows + a_src stay in flight across the FMA block
                ce_c = ellp[beg + bs + 8 + jj];
                LOADROWS(ce_c, hv_n, bs + 8)
                as_c = a_src[(ce_c >> 16) * HEADS + hh];
            }
            const float ea = bf2f(ce & 0xffffu);
            float lg = fmaf(ea, p, as + adq);
            lg = fmaxf(lg, NEG_SLOPE * lg);         // leaky_relu, branchless
            const float ev = (bs + jj < cn) ? __expf(lg) : 0.f;
            zp += ev;
            FMAROWS(ev, hv_c)
            if (last) break;
#pragma unroll
            for (int j = 0; j < 8; ++j) hv_c[j] = hv_n[j];
        }
    }

    // z: reduce per-lane partials across the 8 lanes of this head group
    float z = zp;
    z += __shfl_xor(z, 1, 64);
    z += __shfl_xor(z, 2, 64);
    z += __shfl_xor(z, 4, 64);
    const float rz = 1.f / (z + 1e-16f);
    acc0 *= rz;
    acc1 *= rz;

    const size_t idx = (size_t)n * HC + 2 * l;
    const float2 xv = *reinterpret_cast<const float2*>(x + idx);
    float v0 = acc0 + xv.x + bv.x;
    float v1 = acc1 + xv.y + bv.y;
    float s1 = v0 + v1, s2 = v0 * v0 + v1 * v1;
#pragma unroll
    for (int off = 32; off >= 1; off >>= 1) {
        s1 += __shfl_xor(s1, off, 64);
        s2 += __shfl_xor(s2, off, 64);
    }
    const float mean = s1 * (1.f / HC);
    const float var  = s2 * (1.f / HC) - mean * mean;
    const float inv  = rsqrtf(var + LN_EPS);
    float y0 = (v0 - mean) * inv * gv.x + be.x;
    float y1 = (v1 - mean) * inv * gv.y + be.y;
    y0 = y0 > 0.f ? y0 : expm1f(y0);
    y1 = y1 > 0.f ? y1 : expm1f(y1);
    *reinterpret_cast<float2*>(out + idx) = make_float2(y0, y1);
}

// ---------------------------------------------------------------------------
extern "C" void kernel_launch(void* const* d_in, const int* in_sizes, int n_in,
                              void* d_out, int out_size, void* d_ws, size_t ws_size,
                              hipStream_t stream)
{
    const float* x         = (const float*)d_in[0];
    const int*   ei        = (const int*)d_in[1];
    const float* edge_attr = (const float*)d_in[2];
    const float* W         = (const float*)d_in[3];
    const float* b         = (const float*)d_in[4];
    const float* att_src   = (const float*)d_in[5];
    const float* att_dst   = (const float*)d_in[6];
    const float* att_edge  = (const float*)d_in[7];
    const float* lin_w     = (const float*)d_in[8];
    const float* lin_b     = (const float*)d_in[9];
    const float* gamma     = (const float*)d_in[10];
    const float* beta      = (const float*)d_in[11];

    char* ws = (char*)d_ws;
    bf16*  h     = (bf16*)ws;  ws += (size_t)N_NODES * HC * sizeof(bf16);      // 12.8 MB
    float* a_src = (float*)ws; ws += (size_t)N_NODES * HEADS * sizeof(float);  //  1.6 MB
    float* a_dst = (float*)ws; ws += (size_t)N_NODES * HEADS * sizeof(float);  //  1.6 MB
    int*   cnt   = (int*)ws;   ws += (size_t)CNT_SIZE * sizeof(int);           //  0.2 MB
    unsigned short* Wt = (unsigned short*)ws;
    ws += (size_t)128 * 128 * sizeof(unsigned short);                          //  32 KB
    unsigned int* ellp = (unsigned int*)ws;
    ws += (size_t)(N_NODES * ELL_CAP + 64) * sizeof(unsigned int);             // 12.8 MB + pad

    prep<<<64, 256, 0, stream>>>(W, Wt, cnt);

    fused<<<FUSED_BLOCKS, 256, 0, stream>>>(
        x, Wt, att_src, att_dst, ei, edge_attr, cnt, ellp,
        (unsigned short*)h, a_src, a_dst);

    gather_node<<<N_NODES / 4, 256, 0, stream>>>(
        cnt, ellp, a_src, a_dst, h, x, b, gamma, beta,
        att_edge, lin_w, lin_b, (float*)d_out);
}